// Round 4
// baseline (4053.880 us; speedup 1.0000x reference)
//
#include <hip/hip_runtime.h>
#include <cmath>
#include <complex>
#include <cstring>
#include <cstdint>

#define NN 50000
#define NE 600000

#define ISN 0.51298917604257706f
#define RN  1.4142135623730951f

// ---- CG table offsets (flattened, [d1][d2][d3] row-major) ----
#define CG000 0
#define CG110 1
#define CG220 10
#define CG330 35
#define CG011 84
#define CG101 93
#define CG121 102
#define CG211 147
#define CG231 192
#define CG321 297
#define CG111 402
#define CG221 429
#define CG331 504
#define CGTOT 651

struct CGTab { float v[CGTOT]; };

// ===================== host: real Wigner-3j (mirrors reference) =====================
static double factd(int n){ double r=1.0; for(int i=2;i<=n;++i) r*=(double)i; return r; }

static void cg_complex_h(int j1,int j2,int j3,double* C){
  const int d2=2*j2+1, d3=2*j3+1;
  const int tot=(2*j1+1)*d2*d3;
  for(int i=0;i<tot;++i) C[i]=0.0;
  for(int m1=-j1;m1<=j1;++m1) for(int m2=-j2;m2<=j2;++m2){
    int m3=m1+m2; if(m3<-j3||m3>j3) continue;
    double pref=std::sqrt((double)(2*j3+1)*factd(j3+j1-j2)*factd(j3-j1+j2)*factd(j1+j2-j3)/factd(j1+j2+j3+1));
    pref*=std::sqrt(factd(j3+m3)*factd(j3-m3)*factd(j1-m1)*factd(j1+m1)*factd(j2-m2)*factd(j2+m2));
    double s=0.0;
    for(int k=0;k<=j1+j2-j3;++k){
      int a1=j1+j2-j3-k,a2=j1-m1-k,a3=j2+m2-k,a4=j3-j2+m1+k,a5=j3-j1-m2+k;
      if(a1<0||a2<0||a3<0||a4<0||a5<0) continue;
      double pr=factd(k)*factd(a1)*factd(a2)*factd(a3)*factd(a4)*factd(a5);
      s+=((k&1)?-1.0:1.0)/pr;
    }
    C[(m1+j1)*d2*d3+(m2+j2)*d3+(m3+j3)]=pref*s;
  }
}

typedef std::complex<double> cdbl;

static void real_change_h(int l, cdbl* A){
  int d=2*l+1;
  for(int i=0;i<d*d;++i) A[i]=cdbl(0,0);
  A[l*d+l]=cdbl(1,0);
  const double is2=1.0/std::sqrt(2.0);
  for(int m=1;m<=l;++m){
    double sg=(m&1)?-1.0:1.0;
    A[(l+m)*d+(l-m)]=cdbl(is2,0);
    A[(l+m)*d+(l+m)]=cdbl(sg*is2,0);
    A[(l-m)*d+(l-m)]=cdbl(0,is2);
    A[(l-m)*d+(l+m)]=cdbl(0,-sg*is2);
  }
}

static void real_w3j_h(int l1,int l2,int l3,float* R){
  const int d1=2*l1+1,d2=2*l2+1,d3=2*l3+1;
  double cg[512]; cg_complex_h(l1,l2,l3,cg);
  double w[512];
  for(int a=0;a<d1;++a)for(int b=0;b<d2;++b)for(int m3=-l3;m3<=l3;++m3){
    double sg=((l1-l2-m3)&1)?-1.0:1.0;
    w[a*d2*d3+b*d3+(m3+l3)]=sg/std::sqrt((double)(2*l3+1))*cg[a*d2*d3+b*d3+(-m3+l3)];
  }
  cdbl A1[49],A2[49],A3[49];
  real_change_h(l1,A1); real_change_h(l2,A2); real_change_h(l3,A3);
  double nre=0.0,nim=0.0;
  cdbl T[512];
  for(int i=0;i<d1;++i)for(int j=0;j<d2;++j)for(int k=0;k<d3;++k){
    cdbl s(0,0);
    for(int a=0;a<d1;++a){ cdbl f1=A1[i*d1+a];
      if(f1.real()==0.0&&f1.imag()==0.0) continue;
      for(int b=0;b<d2;++b){ cdbl f2=A2[j*d2+b];
        if(f2.real()==0.0&&f2.imag()==0.0) continue;
        cdbl f12=f1*f2;
        for(int c=0;c<d3;++c){ cdbl f3=A3[k*d3+c];
          if(f3.real()==0.0&&f3.imag()==0.0) continue;
          s+=f12*f3*w[a*d2*d3+b*d3+c];
        }
      }
    }
    T[i*d2*d3+j*d3+k]=s;
    nre+=s.real()*s.real(); nim+=s.imag()*s.imag();
  }
  bool useRe = std::sqrt(nre)>=std::sqrt(nim);
  for(int i=0;i<d1*d2*d3;++i) R[i]=(float)(useRe?T[i].real():T[i].imag());
}

static void build_cg(CGTab& t){
  struct E{int l1,l2,l3,off;};
  const E es[13]={{0,0,0,CG000},{1,1,0,CG110},{2,2,0,CG220},{3,3,0,CG330},
    {0,1,1,CG011},{1,0,1,CG101},{1,2,1,CG121},{2,1,1,CG211},{2,3,1,CG231},
    {3,2,1,CG321},{1,1,1,CG111},{2,2,1,CG221},{3,3,1,CG331}};
  for(int i=0;i<13;++i) real_w3j_h(es[i].l1,es[i].l2,es[i].l3,t.v+es[i].off);
}

// ===================== device helpers =====================
__device__ __forceinline__ void atomicAddF(float* p, float v){
  unsafeAtomicAdd(p, v);
}
__device__ __forceinline__ void ld16f(const float* p, float* d){
  const float4* q=(const float4*)p;
  #pragma unroll
  for(int i=0;i<4;++i){ float4 t=q[i]; d[4*i]=t.x; d[4*i+1]=t.y; d[4*i+2]=t.z; d[4*i+3]=t.w; }
}

// ===================== k_pack: gather/prescale live columns of w2c/w2f =====================
// w2cp: [256][224]  (200 live cols, pad 0)   w2fp: [256][160] (152 live, pad 0)
__global__ void k_pack(const float* __restrict__ w2c, const float* __restrict__ w2f,
                       float* __restrict__ w2cp, float* __restrict__ w2fp){
  int idx = blockIdx.x*256 + threadIdx.x;   // grid 384*256 = 98304 exact
  const float Sc = (float)(1.4142135623730951/(16.0*sqrt(3.0))/sqrt(3.8));
  const float Sf = (float)(1.4142135623730951/(16.0*sqrt(3.0))/sqrt(3.8)*0.5);
  const float A_ = (float)sqrt(0.5);
  const float B_ = (float)sqrt(1.0/48.0);
  if (idx < 256*224){
    int row=idx/224, c=idx%224;
    float v=0.f;
    if (c<200){
      int oc; float s;
      if (c<128){ oc=c; s=0.5f; }
      else if (c<176){ int p=(c-128)>>3, m=(c-128)&7; oc=128+16*p+m; s=A_; }
      else { int p=(c-176)>>3, m=(c-176)&7; oc=224+16*p+m; s=1.0f; }
      v = w2c[row*272+oc]*(Sc*s);
    }
    w2cp[idx]=v;
  } else {
    idx -= 256*224;
    int row=idx/160, c=idx%160;
    float v=0.f;
    if (c<152){
      int oc; float s;
      if (c<8){ oc=8+c; s=0.25f; }
      else if (c<104){ oc=16+(c-8); s=B_; }
      else { oc=208+(c-104); s=B_; }
      v = w2f[row*304+oc]*(Sf*s);
    }
    w2fp[idx]=v;
  }
}

// ===================== k_geom: per-edge SH + length, atomic x0 =====================
__global__ void k_geom(const float* __restrict__ pos, const int* __restrict__ esrc,
                       const int* __restrict__ edst, float* __restrict__ lenb,
                       float* __restrict__ shb, float* __restrict__ x0){
  int e = blockIdx.x*256+threadIdx.x;
  if (e>=NE) return;
  int s=esrc[e], d=edst[e];
  float vx=pos[3*s]-pos[3*d], vy=pos[3*s+1]-pos[3*d+1], vz=pos[3*s+2]-pos[3*d+2];
  float len=sqrtf(vx*vx+vy*vy+vz*vz);
  float inv=1.0f/fmaxf(len,1e-9f);
  float x=vx*inv, y=vy*inv, z=vz*inv;
  float x2=x*x, y2=y*y, z2=z*z;
  float sh[16];
  sh[0]=1.0f;
  sh[1]=1.7320508f*y; sh[2]=1.7320508f*z; sh[3]=1.7320508f*x;
  sh[4]=3.8729833f*x*y; sh[5]=3.8729833f*y*z; sh[6]=1.1180340f*(3.0f*z2-1.0f);
  sh[7]=3.8729833f*x*z; sh[8]=1.9364917f*(x2-y2);
  sh[9]=2.0916501f*y*(3.0f*x2-y2); sh[10]=10.2469508f*x*y*z;
  sh[11]=1.6201852f*y*(5.0f*z2-1.0f); sh[12]=1.3228757f*z*(5.0f*z2-3.0f);
  sh[13]=1.6201852f*x*(5.0f*z2-1.0f); sh[14]=5.1234754f*z*(x2-y2);
  sh[15]=2.0916501f*x*(x2-3.0f*y2);
  lenb[e]=len;
  float4* sp=(float4*)(shb+(size_t)16*e);
  sp[0]=make_float4(sh[0],sh[1],sh[2],sh[3]);
  sp[1]=make_float4(sh[4],sh[5],sh[6],sh[7]);
  sp[2]=make_float4(sh[8],sh[9],sh[10],sh[11]);
  sp[3]=make_float4(sh[12],sh[13],sh[14],sh[15]);
  float* xb=x0+(size_t)16*d;
  #pragma unroll
  for(int i=0;i<16;++i) atomicAddF(xb+i, sh[i]*ISN);
}

// ===================== k_conv: fused h -> GEMM(224c) -> TP -> scatter x1[80] =====================
__global__ __launch_bounds__(256,2)
void k_conv(const int* __restrict__ esrc, const int* __restrict__ edst,
            const float* __restrict__ lenb, const float* __restrict__ shb,
            const float* __restrict__ x0, const float* __restrict__ w1c,
            const float* __restrict__ w2cp, CGTab cgt, float* __restrict__ x1){
  __shared__ union UL {
    struct { float hA[32][64]; float w2s[32][224]; } g;
    float wbuf[64][228];
  } L;
  const int tid=threadIdx.x;
  const int eb=blockIdx.x*64;
  const int sub=tid&7, kk0=tid>>3;
  const int tn=tid&15, tm=tid>>4;
  const int wv=tid>>6, lane=tid&63;
  const int e=eb+lane;

  // --- hoisted epilogue gathers (latency hidden under GEMM) ---
  const int srcn=esrc[e], dstn=edst[e];
  float s1[16], s2[16];
  ld16f(x0+(size_t)16*srcn, s1);
  ld16f(shb+(size_t)16*e,  s2);

  // radial embedding for this thread's 8 staging edges (fixed across K chunks)
  float em0[8],em1[8],em2[8];
  #pragma unroll
  for(int i=0;i<8;++i){
    float len=lenb[eb+8*sub+i];
    float t0=2.0f*(len-1.0f), t1=2.0f*(len-1.5f), t2=2.0f*(len-2.0f);
    em0[i]=expf(-t0*t0)*1.7320508f;
    em1[i]=expf(-t1*t1)*1.7320508f;
    em2[i]=expf(-t2*t2)*1.7320508f;
  }

  float acc[4][14];
  #pragma unroll
  for(int r=0;r<4;++r)
    #pragma unroll
    for(int c=0;c<14;++c) acc[r][c]=0.f;

  for(int kc=0;kc<8;++kc){
    // stage hA[kk][edge]
    {
      int K=kc*32+kk0;
      float a=w1c[K], b=w1c[256+K], c=w1c[512+K];
      float hv[8];
      #pragma unroll
      for(int i=0;i<8;++i) hv[i]=fmaxf(em0[i]*a+em1[i]*b+em2[i]*c,0.f);
      float4* p=(float4*)&L.g.hA[kk0][8*sub];
      p[0]=make_float4(hv[0],hv[1],hv[2],hv[3]);
      p[1]=make_float4(hv[4],hv[5],hv[6],hv[7]);
    }
    // stage w2s (linear copy of 32x224 chunk)
    {
      const float4* src=(const float4*)(w2cp+(size_t)kc*32*224);
      float4* dst=(float4*)&L.g.w2s[0][0];
      #pragma unroll
      for(int i=0;i<7;++i) dst[tid+256*i]=src[tid+256*i];
    }
    __syncthreads();
    #pragma unroll
    for(int kk=0;kk<32;++kk){
      float a0,a1,a2,a3;
      { float4 av=*(const float4*)&L.g.hA[kk][4*tm]; a0=av.x;a1=av.y;a2=av.z;a3=av.w; }
      float b[14];
      #pragma unroll
      for(int s=0;s<7;++s){ float2 bv=*(const float2*)&L.g.w2s[kk][14*tn+2*s]; b[2*s]=bv.x; b[2*s+1]=bv.y; }
      #pragma unroll
      for(int c=0;c<14;++c){
        acc[0][c]+=a0*b[c]; acc[1][c]+=a1*b[c]; acc[2][c]+=a2*b[c]; acc[3][c]+=a3*b[c];
      }
    }
    __syncthreads();
  }

  // weights -> wbuf[edge][col]
  #pragma unroll
  for(int r=0;r<4;++r){
    float* row=&L.wbuf[4*tm+r][14*tn];
    #pragma unroll
    for(int s=0;s<7;++s) *(float2*)&row[2*s]=make_float2(acc[r][2*s],acc[r][2*s+1]);
  }
  __syncthreads();

  // epilogue: lane = edge.
  // wv0 -> 0e ch 0..15 (cols 0..63), wv3 -> 0e ch 16..31 (cols 64..127),
  // wv1 -> 1o ch 32..55 (cols 128..175), wv2 -> 1e ch 56..79 (cols 176..199)
  {
    float* ob=x1+(size_t)80*dstn;
    if (wv==0 || wv==3){
      float T[4];
      T[0]=s1[0]*s2[0]*cgt.v[CG000];
      T[1]=0.f;
      #pragma unroll
      for(int a=0;a<3;++a)
        #pragma unroll
        for(int b=0;b<3;++b) T[1]+=s1[1+a]*s2[1+b]*cgt.v[CG110+3*a+b];
      T[2]=0.f;
      #pragma unroll
      for(int a=0;a<5;++a)
        #pragma unroll
        for(int b=0;b<5;++b) T[2]+=s1[4+a]*s2[4+b]*cgt.v[CG220+5*a+b];
      T[3]=0.f;
      #pragma unroll
      for(int a=0;a<7;++a)
        #pragma unroll
        for(int b=0;b<7;++b) T[3]+=s1[9+a]*s2[9+b]*cgt.v[CG330+7*a+b];
      float ef[16];
      #pragma unroll
      for(int i=0;i<16;++i) ef[i]=0.f;
      if (wv==0){
        // cols 0..63: io=0, 4 paths x 16 muls
        #pragma unroll
        for(int jq=0;jq<16;++jq){
          float4 w=*(const float4*)&L.wbuf[lane][4*jq];
          float wa[4]={w.x,w.y,w.z,w.w};
          #pragma unroll
          for(int t=0;t<4;++t){
            int j=4*jq+t;
            ef[j&15] += wa[t]*T[j>>4];
          }
        }
        #pragma unroll
        for(int m=0;m<16;++m) atomicAddF(ob+m, ef[m]);
      } else {
        // cols 64..127: io=2 (4x8) then io=4 (4x8)
        #pragma unroll
        for(int jq=16;jq<32;++jq){
          float4 w=*(const float4*)&L.wbuf[lane][4*jq];
          float wa[4]={w.x,w.y,w.z,w.w};
          #pragma unroll
          for(int t=0;t<4;++t){
            int j=4*jq+t;
            if (j<96)  ef[(j-64)&7]     += wa[t]*T[(j-64)>>3];
            else       ef[8+((j-96)&7)] += wa[t]*T[(j-96)>>3];
          }
        }
        #pragma unroll
        for(int m=0;m<16;++m) atomicAddF(ob+16+m, ef[m]);
      }
    } else if (wv==1){
      float T[6][3];
      #pragma unroll
      for(int p=0;p<6;++p)
        #pragma unroll
        for(int k=0;k<3;++k) T[p][k]=0.f;
      #pragma unroll
      for(int b=0;b<3;++b){ float pr=s1[0]*s2[1+b];
        #pragma unroll
        for(int k=0;k<3;++k) T[0][k]+=pr*cgt.v[CG011+3*b+k]; }
      #pragma unroll
      for(int a=0;a<3;++a){ float pr=s1[1+a]*s2[0];
        #pragma unroll
        for(int k=0;k<3;++k) T[1][k]+=pr*cgt.v[CG101+3*a+k]; }
      #pragma unroll
      for(int a=0;a<3;++a)
        #pragma unroll
        for(int b=0;b<5;++b){ float pr=s1[1+a]*s2[4+b];
          #pragma unroll
          for(int k=0;k<3;++k) T[2][k]+=pr*cgt.v[CG121+(5*a+b)*3+k]; }
      #pragma unroll
      for(int a=0;a<5;++a)
        #pragma unroll
        for(int b=0;b<3;++b){ float pr=s1[4+a]*s2[1+b];
          #pragma unroll
          for(int k=0;k<3;++k) T[3][k]+=pr*cgt.v[CG211+(3*a+b)*3+k]; }
      #pragma unroll
      for(int a=0;a<5;++a)
        #pragma unroll
        for(int b=0;b<7;++b){ float pr=s1[4+a]*s2[9+b];
          #pragma unroll
          for(int k=0;k<3;++k) T[4][k]+=pr*cgt.v[CG231+(7*a+b)*3+k]; }
      #pragma unroll
      for(int a=0;a<7;++a)
        #pragma unroll
        for(int b=0;b<5;++b){ float pr=s1[9+a]*s2[4+b];
          #pragma unroll
          for(int k=0;k<3;++k) T[5][k]+=pr*cgt.v[CG321+(5*a+b)*3+k]; }
      float ef[24];
      #pragma unroll
      for(int i=0;i<24;++i) ef[i]=0.f;
      #pragma unroll
      for(int jq=32;jq<44;++jq){
        float4 w=*(const float4*)&L.wbuf[lane][4*jq];
        float wa[4]={w.x,w.y,w.z,w.w};
        #pragma unroll
        for(int t=0;t<4;++t){
          int loc=4*jq+t-128; int p=loc>>3, m=loc&7;
          #pragma unroll
          for(int k=0;k<3;++k) ef[3*m+k]+=wa[t]*T[p][k];
        }
      }
      #pragma unroll
      for(int i=0;i<24;++i) atomicAddF(ob+32+i, ef[i]);
    } else {
      float T[3][3];
      #pragma unroll
      for(int p=0;p<3;++p)
        #pragma unroll
        for(int k=0;k<3;++k) T[p][k]=0.f;
      #pragma unroll
      for(int a=0;a<3;++a)
        #pragma unroll
        for(int b=0;b<3;++b){ float pr=s1[1+a]*s2[1+b];
          #pragma unroll
          for(int k=0;k<3;++k) T[0][k]+=pr*cgt.v[CG111+(3*a+b)*3+k]; }
      #pragma unroll
      for(int a=0;a<5;++a)
        #pragma unroll
        for(int b=0;b<5;++b){ float pr=s1[4+a]*s2[4+b];
          #pragma unroll
          for(int k=0;k<3;++k) T[1][k]+=pr*cgt.v[CG221+(5*a+b)*3+k]; }
      #pragma unroll
      for(int a=0;a<7;++a)
        #pragma unroll
        for(int b=0;b<7;++b){ float pr=s1[9+a]*s2[9+b];
          #pragma unroll
          for(int k=0;k<3;++k) T[2][k]+=pr*cgt.v[CG331+(7*a+b)*3+k]; }
      float ef[24];
      #pragma unroll
      for(int i=0;i<24;++i) ef[i]=0.f;
      #pragma unroll
      for(int jq=44;jq<50;++jq){
        float4 w=*(const float4*)&L.wbuf[lane][4*jq];
        float wa[4]={w.x,w.y,w.z,w.w};
        #pragma unroll
        for(int t=0;t<4;++t){
          int loc=4*jq+t-176; int p=loc>>3, m=loc&7;
          #pragma unroll
          for(int k=0;k<3;++k) ef[3*m+k]+=wa[t]*T[p][k];
        }
      }
      #pragma unroll
      for(int i=0;i<24;++i) atomicAddF(ob+56+i, ef[i]);
    }
  }
}

// ===================== k_gate: compact x1[80] -> xg[64] =====================
__global__ void k_gate(const float* __restrict__ x1, float* __restrict__ xg){
  int n=blockIdx.x*256+threadIdx.x;
  if (n>=NN) return;
  float v[80];
  const float4* p=(const float4*)(x1+(size_t)80*n);
  #pragma unroll
  for(int i=0;i<20;++i){ float4 q=p[i]; v[4*i]=q.x; v[4*i+1]=q.y; v[4*i+2]=q.z; v[4*i+3]=q.w; }
  float o[64];
  #pragma unroll
  for(int i=0;i<16;++i) o[i]=fmaxf(v[i],0.f)*RN;
  #pragma unroll
  for(int r=0;r<8;++r){ float g=fmaxf(v[16+r],0.f)*RN;
    #pragma unroll
    for(int k=0;k<3;++k) o[16+3*r+k]=v[32+3*r+k]*g; }
  #pragma unroll
  for(int r=0;r<8;++r){ float g=fmaxf(v[24+r],0.f)*RN;
    #pragma unroll
    for(int k=0;k<3;++k) o[40+3*r+k]=v[56+3*r+k]*g; }
  float4* q=(float4*)(xg+(size_t)64*n);
  #pragma unroll
  for(int i=0;i<16;++i) q[i]=make_float4(o[4*i],o[4*i+1],o[4*i+2],o[4*i+3]);
}

// ===================== k_final: fused h -> GEMM(160c) -> TP -> graph reduce =====================
__global__ __launch_bounds__(256,3)
void k_final(const int* __restrict__ esrc, const int* __restrict__ edst,
             const float* __restrict__ lenb, const float* __restrict__ shb,
             const float* __restrict__ xg, const float* __restrict__ w1f,
             const float* __restrict__ w2fp, CGTab cgt,
             const int* __restrict__ batch, float* __restrict__ out){
  __shared__ union UL {
    struct { float hA[32][64]; float w2s[32][160]; } g;
    float wbuf[64][164];
  } L;
  __shared__ float gacc[16][8];
  const int tid=threadIdx.x;
  if (tid<128) ((float*)gacc)[tid]=0.f;
  const int eb=blockIdx.x*64;
  const int sub=tid&7, kk0=tid>>3;
  const int tn=tid&15, tm=tid>>4;
  const int wv=tid>>6, lane=tid&63;
  const int e=eb+lane;

  // --- hoisted epilogue gathers ---
  const int srcn=esrc[e], dstn=edst[e];
  const int gidx=batch[dstn];
  const float* yp = xg+(size_t)64*srcn;
  float4 s4=*(const float4*)(shb+(size_t)16*e);
  float shv[4]={s4.x,s4.y,s4.z,s4.w};
  float y0[8], yA[24];     // wv0: y0=se lo | wv1: y0=se hi, yA=idx4 | wv2: yA=idx2
  if (wv==0){
    const float4* p=(const float4*)yp;
    float4 t0=p[0], t1=p[1];
    y0[0]=t0.x;y0[1]=t0.y;y0[2]=t0.z;y0[3]=t0.w;
    y0[4]=t1.x;y0[5]=t1.y;y0[6]=t1.z;y0[7]=t1.w;
  } else if (wv==1){
    const float4* p=(const float4*)(yp+8);
    float4 t0=p[0], t1=p[1];
    y0[0]=t0.x;y0[1]=t0.y;y0[2]=t0.z;y0[3]=t0.w;
    y0[4]=t1.x;y0[5]=t1.y;y0[6]=t1.z;y0[7]=t1.w;
    const float4* pa=(const float4*)(yp+40);
    #pragma unroll
    for(int i=0;i<6;++i){ float4 t=pa[i]; yA[4*i]=t.x; yA[4*i+1]=t.y; yA[4*i+2]=t.z; yA[4*i+3]=t.w; }
  } else if (wv==2){
    const float4* pa=(const float4*)(yp+16);
    #pragma unroll
    for(int i=0;i<6;++i){ float4 t=pa[i]; yA[4*i]=t.x; yA[4*i+1]=t.y; yA[4*i+2]=t.z; yA[4*i+3]=t.w; }
  }

  float em0[8],em1[8],em2[8];
  #pragma unroll
  for(int i=0;i<8;++i){
    float len=lenb[eb+8*sub+i];
    float t0=2.0f*(len-1.0f), t1=2.0f*(len-1.5f), t2=2.0f*(len-2.0f);
    em0[i]=expf(-t0*t0)*1.7320508f;
    em1[i]=expf(-t1*t1)*1.7320508f;
    em2[i]=expf(-t2*t2)*1.7320508f;
  }

  float acc[4][10];
  #pragma unroll
  for(int r=0;r<4;++r)
    #pragma unroll
    for(int c=0;c<10;++c) acc[r][c]=0.f;

  for(int kc=0;kc<8;++kc){
    {
      int K=kc*32+kk0;
      float a=w1f[K], b=w1f[256+K], c=w1f[512+K];
      float hv[8];
      #pragma unroll
      for(int i=0;i<8;++i) hv[i]=fmaxf(em0[i]*a+em1[i]*b+em2[i]*c,0.f);
      float4* p=(float4*)&L.g.hA[kk0][8*sub];
      p[0]=make_float4(hv[0],hv[1],hv[2],hv[3]);
      p[1]=make_float4(hv[4],hv[5],hv[6],hv[7]);
    }
    {
      const float4* src=(const float4*)(w2fp+(size_t)kc*32*160);
      float4* dst=(float4*)&L.g.w2s[0][0];
      #pragma unroll
      for(int i=0;i<5;++i) dst[tid+256*i]=src[tid+256*i];
    }
    __syncthreads();
    #pragma unroll
    for(int kk=0;kk<32;++kk){
      float a0,a1,a2,a3;
      { float4 av=*(const float4*)&L.g.hA[kk][4*tm]; a0=av.x;a1=av.y;a2=av.z;a3=av.w; }
      float b[10];
      #pragma unroll
      for(int s=0;s<5;++s){ float2 bv=*(const float2*)&L.g.w2s[kk][10*tn+2*s]; b[2*s]=bv.x; b[2*s+1]=bv.y; }
      #pragma unroll
      for(int c=0;c<10;++c){
        acc[0][c]+=a0*b[c]; acc[1][c]+=a1*b[c]; acc[2][c]+=a2*b[c]; acc[3][c]+=a3*b[c];
      }
    }
    __syncthreads();
  }

  #pragma unroll
  for(int r=0;r<4;++r){
    float* row=&L.wbuf[4*tm+r][10*tn];
    #pragma unroll
    for(int s=0;s<5;++s) *(float2*)&row[2*s]=make_float2(acc[r][2*s],acc[r][2*s+1]);
  }
  __syncthreads();

  // epilogue split across waves 0..2:
  //  wv0: path2 (se) u=0..7   -> cols 8..55   (jq 2..13)
  //  wv1: path1 (tA, cols 0..7, jq 0..1) + path2 u=8..15 -> cols 56..103 (jq 14..25)
  //  wv2: path4 (tC) -> cols 104..151 (jq 26..37)
  if (wv<3){
    float c000=cgt.v[CG000];
    float ef[7];
    #pragma unroll
    for(int i=0;i<7;++i) ef[i]=0.f;
    if (wv==0){
      float du[8];
      #pragma unroll
      for(int u=0;u<8;++u) du[u]=y0[u]*shv[0]*c000;
      #pragma unroll
      for(int jq=2;jq<14;++jq){
        float4 w=*(const float4*)&L.wbuf[lane][4*jq];
        float wa[4]={w.x,w.y,w.z,w.w};
        #pragma unroll
        for(int t=0;t<4;++t){
          int loc=4*jq+t-8;   // 0..47
          ef[1+loc%6] += wa[t]*du[loc/6];
        }
      }
      #pragma unroll
      for(int oc=1;oc<7;++oc) atomicAdd(&gacc[gidx][oc], ef[oc]);
    } else if (wv==1){
      float du2[8];
      #pragma unroll
      for(int u=0;u<8;++u) du2[u]=y0[u]*shv[0]*c000;
      float tA[8];
      #pragma unroll
      for(int u=0;u<8;++u){
        float sa=0.f;
        #pragma unroll
        for(int a=0;a<3;++a)
          #pragma unroll
          for(int b=0;b<3;++b) sa+=yA[3*u+a]*shv[1+b]*cgt.v[CG110+3*a+b];
        tA[u]=sa;
      }
      #pragma unroll
      for(int jq=0;jq<2;++jq){
        float4 w=*(const float4*)&L.wbuf[lane][4*jq];
        float wa[4]={w.x,w.y,w.z,w.w};
        #pragma unroll
        for(int t=0;t<4;++t) ef[0] += wa[t]*tA[4*jq+t];
      }
      #pragma unroll
      for(int jq=14;jq<26;++jq){
        float4 w=*(const float4*)&L.wbuf[lane][4*jq];
        float wa[4]={w.x,w.y,w.z,w.w};
        #pragma unroll
        for(int t=0;t<4;++t){
          int loc=4*jq+t-8;   // 48..95
          ef[1+loc%6] += wa[t]*du2[loc/6-8];
        }
      }
      #pragma unroll
      for(int oc=0;oc<7;++oc) atomicAdd(&gacc[gidx][oc], ef[oc]);
    } else {
      float tC[8];
      #pragma unroll
      for(int u=0;u<8;++u){
        float sc=0.f;
        #pragma unroll
        for(int a=0;a<3;++a)
          #pragma unroll
          for(int b=0;b<3;++b) sc+=yA[3*u+a]*shv[1+b]*cgt.v[CG110+3*a+b];
        tC[u]=sc;
      }
      #pragma unroll
      for(int jq=26;jq<38;++jq){
        float4 w=*(const float4*)&L.wbuf[lane][4*jq];
        float wa[4]={w.x,w.y,w.z,w.w};
        #pragma unroll
        for(int t=0;t<4;++t){
          int loc2=4*jq+t-104;  // 0..47
          ef[1+loc2%6] += wa[t]*tC[loc2/6];
        }
      }
      #pragma unroll
      for(int oc=1;oc<7;++oc) atomicAdd(&gacc[gidx][oc], ef[oc]);
    }
  }
  __syncthreads();
  if (tid<112) atomicAddF(out+tid, gacc[tid/7][tid%7]);
}

// ===================== launch =====================
extern "C" void kernel_launch(void* const* d_in, const int* in_sizes, int n_in,
                              void* d_out, int out_size, void* d_ws, size_t ws_size,
                              hipStream_t stream) {
  (void)in_sizes; (void)n_in; (void)out_size; (void)ws_size;
  const float* pos  = (const float*)d_in[0];
  const int*   batch= (const int*)d_in[1];
  const int*   esrc = (const int*)d_in[2];
  const int*   edst = (const int*)d_in[3];
  const float* w1c  = (const float*)d_in[4];
  const float* w2c  = (const float*)d_in[5];
  const float* w1f  = (const float*)d_in[6];
  const float* w2f  = (const float*)d_in[7];
  float* out = (float*)d_out;
  char* ws = (char*)d_ws;

  const size_t OFF_W2CP = 0;            // 256*224*4 = 229376
  const size_t OFF_W2FP = 229376;       // 256*160*4 = 163840
  const size_t OFF_LEN  = 393216;       // NE*4      = 2400000
  const size_t OFF_SH   = 2793216;      // NE*16*4   = 38400000
  const size_t OFF_X0   = 41193216;     // NN*16*4   = 3200000
  const size_t OFF_X1   = 44393216;     // NN*80*4   = 16000000
  const size_t OFF_XG   = 60393216;     // NN*64*4   = 12800000 -> 73193216 total

  float* w2cp=(float*)(ws+OFF_W2CP);
  float* w2fp=(float*)(ws+OFF_W2FP);
  float* lenb=(float*)(ws+OFF_LEN);
  float* shb =(float*)(ws+OFF_SH);
  float* x0  =(float*)(ws+OFF_X0);
  float* x1  =(float*)(ws+OFF_X1);
  float* xg  =(float*)(ws+OFF_XG);

  static CGTab hostCG;
  build_cg(hostCG);   // recomputed every call (deterministic), travels as kernarg

  hipMemsetAsync(x0, 0, (size_t)NN*16*4, stream);
  hipMemsetAsync(x1, 0, (size_t)NN*80*4, stream);
  hipMemsetAsync(out, 0, 112*sizeof(float), stream);

  k_pack <<<384, 256, 0, stream>>>(w2c, w2f, w2cp, w2fp);
  k_geom <<<(NE+255)/256, 256, 0, stream>>>(pos, esrc, edst, lenb, shb, x0);
  k_conv <<<NE/64, 256, 0, stream>>>(esrc, edst, lenb, shb, x0, w1c, w2cp, hostCG, x1);
  k_gate <<<(NN+255)/256, 256, 0, stream>>>(x1, xg);
  k_final<<<NE/64, 256, 0, stream>>>(esrc, edst, lenb, shb, xg, w1f, w2fp, hostCG, batch, out);
}